// Round 8
// baseline (391.419 us; speedup 1.0000x reference)
//
#include <hip/hip_runtime.h>
#include <stdint.h>

#define N_ROWS 65536
#define K_DIM  1024
#define J_OUT  256
#define ROWS_PB 32        // rows per block
#define NT 32             // K-steps of 32
#define THREADS 512       // 8 waves, each owns 64 fused cols x 32 rows

typedef _Float16 half8 __attribute__((ext_vector_type(8)));
typedef float    f32x4 __attribute__((ext_vector_type(4)));

// ---------------- threefry2x32, key=(0,42) — partitionable, XOR-fold -------
// bits = b1 ^ b2 of threefry2x32(k1=0,k2=42, x0=0, x1=i).  (Verified R5.)
__device__ __forceinline__ uint32_t tf_bits_xor(uint32_t ctr) {
  const uint32_t ks0 = 0u, ks1 = 42u, ks2 = 0x1BD11BF0u;
  uint32_t x0 = 0u;
  uint32_t x1 = ctr + ks1;
#define TF_R(rr) x0 += x1; x1 = ((x1 << rr) | (x1 >> (32 - rr))) ^ x0;
  TF_R(13) TF_R(15) TF_R(26) TF_R(6)
  x0 += ks1; x1 += ks2 + 1u;
  TF_R(17) TF_R(29) TF_R(16) TF_R(24)
  x0 += ks2; x1 += ks0 + 2u;
  TF_R(13) TF_R(15) TF_R(26) TF_R(6)
  x0 += ks0; x1 += ks1 + 3u;
  TF_R(17) TF_R(29) TF_R(16) TF_R(24)
  x0 += ks1; x1 += ks2 + 4u;
  TF_R(13) TF_R(15) TF_R(26) TF_R(6)
  x0 += ks2; x1 += ks0 + 5u;
#undef TF_R
  return x0 ^ x1;
}

// uniform(lo=nextafter(-1,0),hi=1) then sqrt(2)*erfinv (XLA Giles). Verified R5.
__device__ __forceinline__ float eps_from_bits(uint32_t bits) {
  float f = __uint_as_float((bits >> 9) | 0x3F800000u) - 1.0f;
  float u = fmaxf(-0.99999994f, f * 2.0f - 0.99999994f);
  float w = -log1pf(-u * u);
  float p;
  if (w < 5.0f) {
    w = w - 2.5f;
    p = 2.81022636e-08f;
    p = fmaf(p, w, 3.43273939e-07f);
    p = fmaf(p, w, -3.5233877e-06f);
    p = fmaf(p, w, -4.39150654e-06f);
    p = fmaf(p, w, 0.00021858087f);
    p = fmaf(p, w, -0.00125372503f);
    p = fmaf(p, w, -0.00417768164f);
    p = fmaf(p, w, 0.246640727f);
    p = fmaf(p, w, 1.50140941f);
  } else {
    w = sqrtf(w) - 3.0f;
    p = -0.000200214257f;
    p = fmaf(p, w, 0.000100950558f);
    p = fmaf(p, w, 0.00134934322f);
    p = fmaf(p, w, -0.00367342844f);
    p = fmaf(p, w, 0.00573950773f);
    p = fmaf(p, w, -0.0076224613f);
    p = fmaf(p, w, -0.00943887047f);
    p = fmaf(p, w, 1.00167406f);
    p = fmaf(p, w, 2.83297682f);
  }
  return 1.41421354f * (p * u);
}

// ---------------- W pre-pack: f32 -> f16 in MFMA B-fragment order ----------
// halves index = ((t*512 + j)*4 + g)*8 + e  holds  W_head[j][k = t*32+g*8+e][c]
//   j = 0..511: head h=(j>>4)&1 (0=mu,1=log_std), col c = (j>>5)*16 + (j&15)
__global__ void pack_w_kernel(const float* __restrict__ Wmu,
                              const float* __restrict__ Wls,
                              _Float16* __restrict__ wt) {
  const int chunk = blockIdx.x * blockDim.x + threadIdx.x;  // 0..65535
  const int g = chunk & 3;
  const int j = (chunk >> 2) & 511;
  const int t = chunk >> 11;
  const int k0 = t * 32 + g * 8;
  const int h = (j >> 4) & 1;
  const int c = ((j >> 5) << 4) | (j & 15);
  const float* W = h ? Wls : Wmu;
  half8 v;
#pragma unroll
  for (int e = 0; e < 8; ++e) v[e] = (_Float16)W[(size_t)(k0 + e) * J_OUT + c];
  *(half8*)(wt + (size_t)chunk * 8) = v;
}

// ---------------- fused GEMM + heads + sampling ----------------------------
// Wave tile 32 rows x 64 fused cols: acc[2][4] (32 regs). 4 waves/SIMD via
// __launch_bounds__(512,4) so load latency hides across waves. No LDS / no
// barriers in the K-loop. Epilogue recomputes per-array values from live acc
// (no spillable buffers), LDS-transposes, writes full lines.
__global__ __launch_bounds__(THREADS, 4)
void fused_heads_kernel(const float* __restrict__ x,
                        const _Float16* __restrict__ wt,
                        const float* __restrict__ b_mu,
                        const float* __restrict__ b_ls,
                        float* __restrict__ out) {
  __shared__ __align__(16) float ebuf[ROWS_PB * 260];   // 33.3 KiB
  const int tid  = threadIdx.x;
  const int lane = tid & 63;
  const int w    = tid >> 6;        // wave 0..7 -> fused cols w*64..w*64+63
  const int rowbase = blockIdx.x * ROWS_PB;

  // A: lane (r=lane&15, g=lane>>4) reads x[rowbase + m*16 + r][t*32 + g*8 ..]
  const float* aBase = x + (size_t)(rowbase + (lane & 15)) * K_DIM
                         + (lane >> 4) * 8;
  // B: frag n is one dwordx4 at bBase + t*16384 + n*512 (1KB contiguous/wave)
  const _Float16* bBase = wt + ((size_t)(w * 64 + (lane & 15)) * 32
                                + (lane >> 4) * 8);

  f32x4 acc[2][4] = {};

  for (int t = 0; t < NT; ++t) {
    const float* ap = aBase + t * 32;
    const _Float16* bp = bBase + (size_t)t * 16384;
    half8 af[2], bf[4];
#pragma unroll
    for (int n = 0; n < 4; ++n) bf[n] = *(const half8*)(bp + n * 512);
#pragma unroll
    for (int m = 0; m < 2; ++m) {
      const f32x4 lo = *(const f32x4*)(ap + (size_t)m * 16 * K_DIM);
      const f32x4 hi = *(const f32x4*)(ap + (size_t)m * 16 * K_DIM + 4);
#pragma unroll
      for (int e = 0; e < 4; ++e) { af[m][e] = (_Float16)lo[e]; af[m][e + 4] = (_Float16)hi[e]; }
    }
#pragma unroll
    for (int m = 0; m < 2; ++m)
#pragma unroll
      for (int n = 0; n < 4; ++n)
        acc[m][n] = __builtin_amdgcn_mfma_f32_16x16x32_f16(af[m], bf[n], acc[m][n], 0, 0, 0);
  }

  // ---- epilogue ----
  // fused col j = w*64 + n*16 + colq: n=2q   -> mean head, c = w*32 + q*16 + colq
  //                                   n=2q+1 -> log_std head, same c
  float* out_mean = out;
  float* out_var  = out + (size_t)N_ROWS * J_OUT;
  float* out_z    = out + 2 * (size_t)N_ROWS * J_OUT;
  const int colq = lane & 15;
  const int g4   = (lane >> 4) * 4;
  float bmq[2], blq[2];
#pragma unroll
  for (int q = 0; q < 2; ++q) {
    const int c = w * 32 + q * 16 + colq;
    bmq[q] = b_mu[c];
    blq[q] = b_ls[c];
  }

#pragma unroll
  for (int arr = 0; arr < 3; ++arr) {
#pragma unroll
    for (int m = 0; m < 2; ++m)
#pragma unroll
      for (int q = 0; q < 2; ++q) {
        const int lcol = w * 32 + q * 16 + colq;
#pragma unroll
        for (int e = 0; e < 4; ++e) {
          const int lrow = m * 16 + g4 + e;
          float val;
          if (arr == 0) {
            val = acc[m][2 * q][e] + bmq[q];
          } else if (arr == 1) {
            val = __expf(2.0f * (acc[m][2 * q + 1][e] + blq[q]));
          } else {
            const float mean = acc[m][2 * q][e] + bmq[q];
            const float var  = __expf(2.0f * (acc[m][2 * q + 1][e] + blq[q]));
            const uint32_t ctr = (uint32_t)((rowbase + lrow) * J_OUT + lcol);
            val = fmaf(sqrtf(var), eps_from_bits(tf_bits_xor(ctr)), mean);
          }
          ebuf[lrow * 260 + lcol] = val;
        }
      }
    __syncthreads();
    float* oarr = (arr == 0) ? out_mean : (arr == 1) ? out_var : out_z;
#pragma unroll
    for (int i = 0; i < 4; ++i) {
      const int idx = i * THREADS + tid;          // 0..2047
      const int r  = idx >> 6;                    // 0..31
      const int c4 = idx & 63;                    // float4 index in row
      const f32x4 v = *(const f32x4*)(ebuf + r * 260 + c4 * 4);
      *(f32x4*)(oarr + (size_t)(rowbase + r) * J_OUT + c4 * 4) = v;
    }
    __syncthreads();
  }
}

extern "C" void kernel_launch(void* const* d_in, const int* in_sizes, int n_in,
                              void* d_out, int out_size, void* d_ws, size_t ws_size,
                              hipStream_t stream) {
  const float* x   = (const float*)d_in[0];
  const float* Wmu = (const float*)d_in[1];
  const float* bmu = (const float*)d_in[2];
  const float* Wls = (const float*)d_in[3];
  const float* bls = (const float*)d_in[4];
  float* out = (float*)d_out;
  _Float16* wt = (_Float16*)d_ws;   // 1 MiB scratch

  pack_w_kernel<<<256, 256, 0, stream>>>(Wmu, Wls, wt);
  fused_heads_kernel<<<N_ROWS / ROWS_PB, THREADS, 0, stream>>>(x, wt, bmu, bls, out);
}

// Round 9
// 223.122 us; speedup vs baseline: 1.7543x; 1.7543x over previous
//
#include <hip/hip_runtime.h>
#include <stdint.h>

#define N_ROWS 65536
#define K_DIM  1024
#define J_OUT  256
#define ROWS_PB 32        // rows per block
#define NT64 16           // K-steps of 64
#define THREADS 512       // 8 waves, each owns 64 fused cols x 32 rows

typedef _Float16 half8 __attribute__((ext_vector_type(8)));
typedef _Float16 half4 __attribute__((ext_vector_type(4)));
typedef float    f32x4 __attribute__((ext_vector_type(4)));

// ---------------- threefry2x32, key=(0,42) — partitionable, XOR-fold -------
// bits = b1 ^ b2 of threefry2x32(k1=0,k2=42, x0=0, x1=i).  (Verified R5.)
__device__ __forceinline__ uint32_t tf_bits_xor(uint32_t ctr) {
  const uint32_t ks0 = 0u, ks1 = 42u, ks2 = 0x1BD11BF0u;
  uint32_t x0 = 0u;
  uint32_t x1 = ctr + ks1;
#define TF_R(rr) x0 += x1; x1 = ((x1 << rr) | (x1 >> (32 - rr))) ^ x0;
  TF_R(13) TF_R(15) TF_R(26) TF_R(6)
  x0 += ks1; x1 += ks2 + 1u;
  TF_R(17) TF_R(29) TF_R(16) TF_R(24)
  x0 += ks2; x1 += ks0 + 2u;
  TF_R(13) TF_R(15) TF_R(26) TF_R(6)
  x0 += ks0; x1 += ks1 + 3u;
  TF_R(17) TF_R(29) TF_R(16) TF_R(24)
  x0 += ks1; x1 += ks2 + 4u;
  TF_R(13) TF_R(15) TF_R(26) TF_R(6)
  x0 += ks2; x1 += ks0 + 5u;
#undef TF_R
  return x0 ^ x1;
}

// uniform(lo=nextafter(-1,0),hi=1) then sqrt(2)*erfinv (XLA Giles). Verified R5.
__device__ __forceinline__ float eps_from_bits(uint32_t bits) {
  float f = __uint_as_float((bits >> 9) | 0x3F800000u) - 1.0f;
  float u = fmaxf(-0.99999994f, f * 2.0f - 0.99999994f);
  float w = -log1pf(-u * u);
  float p;
  if (w < 5.0f) {
    w = w - 2.5f;
    p = 2.81022636e-08f;
    p = fmaf(p, w, 3.43273939e-07f);
    p = fmaf(p, w, -3.5233877e-06f);
    p = fmaf(p, w, -4.39150654e-06f);
    p = fmaf(p, w, 0.00021858087f);
    p = fmaf(p, w, -0.00125372503f);
    p = fmaf(p, w, -0.00417768164f);
    p = fmaf(p, w, 0.246640727f);
    p = fmaf(p, w, 1.50140941f);
  } else {
    w = sqrtf(w) - 3.0f;
    p = -0.000200214257f;
    p = fmaf(p, w, 0.000100950558f);
    p = fmaf(p, w, 0.00134934322f);
    p = fmaf(p, w, -0.00367342844f);
    p = fmaf(p, w, 0.00573950773f);
    p = fmaf(p, w, -0.0076224613f);
    p = fmaf(p, w, -0.00943887047f);
    p = fmaf(p, w, 1.00167406f);
    p = fmaf(p, w, 2.83297682f);
  }
  return 1.41421354f * (p * u);
}

// ---------------- W pre-pack: f32->f16, per-wave-contiguous B fragments ----
// halves idx = (((t32*8 + w)*4 + n)*64 + lane)*8 + e
//   holds W_head(n&1)[k = t32*32 + (lane>>4)*8 + e][c = w*32 + (n>>1)*16 + (lane&15)]
// So wave w's bf[n] at K-step t32 is ONE fully-contiguous 1KB dwordx4 load.
__global__ void pack_w_kernel(const float* __restrict__ Wmu,
                              const float* __restrict__ Wls,
                              _Float16* __restrict__ wt) {
  const int chunk = blockIdx.x * blockDim.x + threadIdx.x;  // 0..65535
  const int lane = chunk & 63;
  const int n = (chunk >> 6) & 3;
  const int w = (chunk >> 8) & 7;
  const int t = chunk >> 11;
  const int k0 = t * 32 + (lane >> 4) * 8;
  const int c  = w * 32 + (n >> 1) * 16 + (lane & 15);
  const float* W = (n & 1) ? Wls : Wmu;
  half8 v;
#pragma unroll
  for (int e = 0; e < 8; ++e) v[e] = (_Float16)W[(size_t)(k0 + e) * J_OUT + c];
  *(half8*)(wt + (size_t)chunk * 8) = v;
}

// ---------------- fused GEMM + heads + sampling ----------------------------
// A staged once/block into LDS (kills 8x duplicate TCP traffic + row scatter);
// B-frags are contiguous 1KB/wave loads from packed wt (L2-resident).
__global__ __launch_bounds__(THREADS, 4)
void fused_heads_kernel(const float* __restrict__ x,
                        const _Float16* __restrict__ wt,
                        const float* __restrict__ b_mu,
                        const float* __restrict__ b_ls,
                        float* __restrict__ out) {
  // A double buffer: [2][32 rows][80 halves] (64 k + 16-half pad -> 2-way banks)
  __shared__ __align__(16) _Float16 Abuf[2][ROWS_PB * 80];      // 10 KiB
  __shared__ __align__(16) float ebuf[ROWS_PB * 260];           // 33.3 KiB
  const int tid  = threadIdx.x;
  const int lane = tid & 63;
  const int w    = tid >> 6;        // wave 0..7 -> fused cols w*64..w*64+63
  const int rowbase = blockIdx.x * ROWS_PB;

  // staging: thread -> (row = tid>>4, 4-float chunk kc = tid&15) of K64 slab
  const int srow = tid >> 4, skc = tid & 15;
  const float* sp = x + (size_t)(rowbase + srow) * K_DIM + skc * 4;
  const int swaddr = srow * 80 + skc * 4;   // halves

  // A fragment read base: lane (r = lane&15, g = lane>>4), +m*16*80, +ks*32
  const int arbase = (lane & 15) * 80 + (lane >> 4) * 8;
  // B: wave-contiguous; frag n at bbase + t32*16384 + n*512 halves
  const _Float16* bbase = wt + w * 2048 + lane * 8;

  f32x4 acc[2][4] = {};

  // prologue: stage K64 slab 0 into buf 0
  {
    const f32x4 v = *(const f32x4*)(sp);
    half4 h;
#pragma unroll
    for (int e = 0; e < 4; ++e) h[e] = (_Float16)v[e];
    *(half4*)(&Abuf[0][swaddr]) = h;
  }
  __syncthreads();

#pragma unroll 2
  for (int t = 0; t < NT64; ++t) {
    const _Float16* Ar = &Abuf[t & 1][0];
    _Float16* Aw = &Abuf[(t + 1) & 1][0];

    // issue B loads for both K32 sub-steps (contiguous 1KB per instr)
    half8 bf[2][4];
#pragma unroll
    for (int ks = 0; ks < 2; ++ks) {
      const _Float16* bp = bbase + (size_t)(2 * t + ks) * 16384;
#pragma unroll
      for (int n = 0; n < 4; ++n) bf[ks][n] = *(const half8*)(bp + n * 512);
    }
    // A fragments from LDS
    half8 af[2][2];
#pragma unroll
    for (int ks = 0; ks < 2; ++ks)
#pragma unroll
      for (int m = 0; m < 2; ++m)
        af[ks][m] = *(const half8*)(Ar + m * 1280 + ks * 32 + arbase);
    // prefetch next K64 slab of x
    f32x4 apre;
    if (t + 1 < NT64) apre = *(const f32x4*)(sp + (t + 1) * 64);

#pragma unroll
    for (int ks = 0; ks < 2; ++ks)
#pragma unroll
      for (int m = 0; m < 2; ++m)
#pragma unroll
        for (int n = 0; n < 4; ++n)
          acc[m][n] = __builtin_amdgcn_mfma_f32_16x16x32_f16(af[ks][m], bf[ks][n], acc[m][n], 0, 0, 0);

    if (t + 1 < NT64) {
      half4 h;
#pragma unroll
      for (int e = 0; e < 4; ++e) h[e] = (_Float16)apre[e];
      *(half4*)(Aw + swaddr) = h;
    }
    __syncthreads();
  }

  // ---- epilogue (unchanged from R8: spill-free, full-line writes) ----
  float* out_mean = out;
  float* out_var  = out + (size_t)N_ROWS * J_OUT;
  float* out_z    = out + 2 * (size_t)N_ROWS * J_OUT;
  const int colq = lane & 15;
  const int g4   = (lane >> 4) * 4;
  float bmq[2], blq[2];
#pragma unroll
  for (int q = 0; q < 2; ++q) {
    const int c = w * 32 + q * 16 + colq;
    bmq[q] = b_mu[c];
    blq[q] = b_ls[c];
  }

#pragma unroll
  for (int arr = 0; arr < 3; ++arr) {
#pragma unroll
    for (int m = 0; m < 2; ++m)
#pragma unroll
      for (int q = 0; q < 2; ++q) {
        const int lcol = w * 32 + q * 16 + colq;
#pragma unroll
        for (int e = 0; e < 4; ++e) {
          const int lrow = m * 16 + g4 + e;
          float val;
          if (arr == 0) {
            val = acc[m][2 * q][e] + bmq[q];
          } else if (arr == 1) {
            val = __expf(2.0f * (acc[m][2 * q + 1][e] + blq[q]));
          } else {
            const float mean = acc[m][2 * q][e] + bmq[q];
            const float var  = __expf(2.0f * (acc[m][2 * q + 1][e] + blq[q]));
            const uint32_t ctr = (uint32_t)((rowbase + lrow) * J_OUT + lcol);
            val = fmaf(sqrtf(var), eps_from_bits(tf_bits_xor(ctr)), mean);
          }
          ebuf[lrow * 260 + lcol] = val;
        }
      }
    __syncthreads();
    float* oarr = (arr == 0) ? out_mean : (arr == 1) ? out_var : out_z;
#pragma unroll
    for (int i = 0; i < 4; ++i) {
      const int idx = i * THREADS + tid;          // 0..2047
      const int r  = idx >> 6;                    // 0..31
      const int c4 = idx & 63;                    // float4 index in row
      const f32x4 v = *(const f32x4*)(ebuf + r * 260 + c4 * 4);
      *(f32x4*)(oarr + (size_t)(rowbase + r) * J_OUT + c4 * 4) = v;
    }
    __syncthreads();
  }
}

extern "C" void kernel_launch(void* const* d_in, const int* in_sizes, int n_in,
                              void* d_out, int out_size, void* d_ws, size_t ws_size,
                              hipStream_t stream) {
  const float* x   = (const float*)d_in[0];
  const float* Wmu = (const float*)d_in[1];
  const float* bmu = (const float*)d_in[2];
  const float* Wls = (const float*)d_in[3];
  const float* bls = (const float*)d_in[4];
  float* out = (float*)d_out;
  _Float16* wt = (_Float16*)d_ws;   // 1 MiB scratch

  pack_w_kernel<<<256, 256, 0, stream>>>(Wmu, Wls, wt);
  fused_heads_kernel<<<N_ROWS / ROWS_PB, THREADS, 0, stream>>>(x, wt, bmu, bls, out);
}